// Round 1
// baseline (201.942 us; speedup 1.0000x reference)
//
#include <hip/hip_runtime.h>

#define Bq 256
#define Nq 128
#define Cq 256
#define TP 8   // particles per block in the fused kernel

// -------- kernel 1: per-batch min(eta), min(phi) -> grid indices --------
__global__ __launch_bounds__(128) void idx_kernel(const float* __restrict__ eta,
                                                  const float* __restrict__ phi,
                                                  int* __restrict__ ge,
                                                  int* __restrict__ gp) {
    int b = blockIdx.x;
    int t = threadIdx.x;  // 0..127
    float e = eta[b * Nq + t];
    float p = phi[b * Nq + t];
    float emin = e, pmin = p;
#pragma unroll
    for (int off = 32; off > 0; off >>= 1) {  // wave64 full reduce
        emin = fminf(emin, __shfl_down(emin, off));
        pmin = fminf(pmin, __shfl_down(pmin, off));
    }
    __shared__ float se[2], sp[2];
    int wave = t >> 6;
    if ((t & 63) == 0) { se[wave] = emin; sp[wave] = pmin; }
    __syncthreads();
    float Emin = fminf(se[0], se[1]);
    float Pmin = fminf(sp[0], sp[1]);
    // match numpy bit-for-bit: fp32 subtract, fp32 divide by 0.05, trunc cast
    ge[b * Nq + t] = (int)((e - Emin) / 0.05f);
    gp[b * Nq + t] = (int)((p - Pmin) / 0.05f);
}

// -------- kernel 2: fused conv-at-particles + dense + LN + residual --------
__global__ __launch_bounds__(256) void fused_kernel(
    const float* __restrict__ x, const int* __restrict__ ge, const int* __restrict__ gp,
    const float* __restrict__ ck, const float* __restrict__ cb,
    const float* __restrict__ dw, const float* __restrict__ db,
    const float* __restrict__ gamma, const float* __restrict__ beta,
    float* __restrict__ out) {
    const int blk = blockIdx.x;
    const int b  = blk / (Nq / TP);
    const int p0 = (blk % (Nq / TP)) * TP;
    const int t  = threadIdx.x;  // channel index

    __shared__ int   s_ge[Nq], s_gp[Nq];
    __shared__ int   s_cnt[TP];
    __shared__ unsigned short s_list[TP][Nq];  // m | (kidx<<8)
    __shared__ float s_conv[TP][Cq];
    __shared__ float s_red[TP][4], s_red2[TP][4];

    if (t < Nq) { s_ge[t] = ge[b * Nq + t]; s_gp[t] = gp[b * Nq + t]; }
    if (t < TP) s_cnt[t] = 0;
    __syncthreads();

    // build neighbor match lists (condition is uniform across the block's waves
    // only in (m,p): threads 0..127 each handle one source particle m)
    if (t < Nq) {
        int mh = s_ge[t], mw = s_gp[t];
#pragma unroll
        for (int p = 0; p < TP; ++p) {
            int dh = mh - s_ge[p0 + p];
            int dv = mw - s_gp[p0 + p];
            if (dh >= -1 && dh <= 1 && dv >= -1 && dv <= 1) {
                int k = (dh + 1) * 3 + (dv + 1);  // cross-correlation index
                int pos = atomicAdd(&s_cnt[p], 1);
                s_list[p][pos] = (unsigned short)(t | (k << 8));
            }
        }
    }
    __syncthreads();

    // conv output at each of the TP gathered positions, channel t
    const float bias_c = cb[t];
#pragma unroll
    for (int p = 0; p < TP; ++p) {
        float acc = bias_c;
        int cnt = s_cnt[p];
        for (int i = 0; i < cnt; ++i) {
            int e = s_list[p][i];
            int m = e & 255;
            int k = e >> 8;
            acc += ck[k * Cq + t] * x[(b * Nq + m) * Cq + t];
        }
        s_conv[p][t] = acc;
    }
    __syncthreads();

    // dense: y[p][t] = db[t] + sum_c s_conv[p][c] * W[c][t]
    float y[TP];
#pragma unroll
    for (int p = 0; p < TP; ++p) y[p] = db[t];
    for (int c = 0; c < Cq; ++c) {
        float wv = dw[c * Cq + t];  // coalesced; reused TP times
#pragma unroll
        for (int p = 0; p < TP; ++p) y[p] += s_conv[p][c] * wv;  // LDS broadcast
    }

    // layer norm: per-particle mean/var over the 256 channels
    int wave = t >> 6;
#pragma unroll
    for (int p = 0; p < TP; ++p) {
        float s = y[p], s2 = y[p] * y[p];
#pragma unroll
        for (int off = 32; off > 0; off >>= 1) {
            s  += __shfl_down(s, off);
            s2 += __shfl_down(s2, off);
        }
        if ((t & 63) == 0) { s_red[p][wave] = s; s_red2[p][wave] = s2; }
    }
    __syncthreads();

    const float g = gamma[t], be = beta[t];
#pragma unroll
    for (int p = 0; p < TP; ++p) {
        float s  = s_red[p][0]  + s_red[p][1]  + s_red[p][2]  + s_red[p][3];
        float s2 = s_red2[p][0] + s_red2[p][1] + s_red2[p][2] + s_red2[p][3];
        float mean = s * (1.0f / Cq);
        float var  = s2 * (1.0f / Cq) - mean * mean;
        float inv  = rsqrtf(var + 1e-6f);
        int off = (b * Nq + p0 + p) * Cq + t;
        out[off] = x[off] + (y[p] - mean) * inv * g + be;
    }
}

extern "C" void kernel_launch(void* const* d_in, const int* in_sizes, int n_in,
                              void* d_out, int out_size, void* d_ws, size_t ws_size,
                              hipStream_t stream) {
    const float* x     = (const float*)d_in[0];
    const float* eta   = (const float*)d_in[1];
    const float* phi   = (const float*)d_in[2];
    const float* ck    = (const float*)d_in[3];
    const float* cb    = (const float*)d_in[4];
    const float* dw    = (const float*)d_in[5];
    const float* db    = (const float*)d_in[6];
    const float* gamma = (const float*)d_in[7];
    const float* beta  = (const float*)d_in[8];
    float* out = (float*)d_out;

    int* ge = (int*)d_ws;
    int* gp = ge + Bq * Nq;

    idx_kernel<<<Bq, Nq, 0, stream>>>(eta, phi, ge, gp);
    fused_kernel<<<Bq * (Nq / TP), Cq, 0, stream>>>(x, ge, gp, ck, cb, dw, db,
                                                    gamma, beta, out);
}

// Round 2
// 165.260 us; speedup vs baseline: 1.2220x; 1.2220x over previous
//
#include <hip/hip_runtime.h>

typedef __attribute__((ext_vector_type(8))) short bf16x8;
typedef __attribute__((ext_vector_type(4))) float f32x4;

#define Bq 256
#define Nq 128
#define Cq 256
#define TP 64   // particles per fused block (M of the per-block GEMM)

__device__ __forceinline__ unsigned short f2bf(float f) {
    unsigned int u = __float_as_uint(f);
    u += 0x7fffu + ((u >> 16) & 1u);   // RNE
    return (unsigned short)(u >> 16);
}

// -------- kernel 0: pack dense_w fp32 -> bf16 in MFMA B-fragment order ------
// wp[((kt*16 + nt)*64 + lane)*8 + j] = W[k = kt*32 + (lane>>4)*8 + j][n = nt*16 + (lane&15)]
__global__ __launch_bounds__(256) void wpack_kernel(const float* __restrict__ dw,
                                                    unsigned short* __restrict__ wp) {
    int tid = blockIdx.x * 256 + threadIdx.x;   // 0..65535
    int j    = tid & 7;
    int lane = (tid >> 3) & 63;
    int nt   = (tid >> 9) & 15;
    int kt   = tid >> 13;
    int k = kt * 32 + (lane >> 4) * 8 + j;
    int n = nt * 16 + (lane & 15);
    wp[tid] = f2bf(dw[k * Cq + n]);
}

// -------- kernel 1: per-batch min(eta), min(phi) -> grid indices --------
__global__ __launch_bounds__(128) void idx_kernel(const float* __restrict__ eta,
                                                  const float* __restrict__ phi,
                                                  int* __restrict__ ge,
                                                  int* __restrict__ gp) {
    int b = blockIdx.x;
    int t = threadIdx.x;
    float e = eta[b * Nq + t];
    float p = phi[b * Nq + t];
    float emin = e, pmin = p;
#pragma unroll
    for (int off = 32; off > 0; off >>= 1) {
        emin = fminf(emin, __shfl_down(emin, off));
        pmin = fminf(pmin, __shfl_down(pmin, off));
    }
    __shared__ float se[2], sp[2];
    int wave = t >> 6;
    if ((t & 63) == 0) { se[wave] = emin; sp[wave] = pmin; }
    __syncthreads();
    float Emin = fminf(se[0], se[1]);
    float Pmin = fminf(sp[0], sp[1]);
    ge[b * Nq + t] = (int)((e - Emin) / 0.05f);
    gp[b * Nq + t] = (int)((p - Pmin) / 0.05f);
}

// -------- kernel 2: fused conv-at-particles + MFMA dense + LN + residual ----
__global__ __launch_bounds__(256, 2) void fused_kernel(
    const float* __restrict__ x, const int* __restrict__ ge, const int* __restrict__ gp,
    const float* __restrict__ ck, const float* __restrict__ cb,
    const unsigned short* __restrict__ wp, const float* __restrict__ db,
    const float* __restrict__ gamma, const float* __restrict__ beta,
    float* __restrict__ out) {
    const int b  = blockIdx.x >> 1;
    const int p0 = (blockIdx.x & 1) * TP;
    const int t  = threadIdx.x;
    const int lane = t & 63, wave = t >> 6;

    __shared__ int s_ge[Nq], s_gp[Nq];
    __shared__ float s_ck[9 * Cq];
    __shared__ int s_cnt[TP][4];
    __shared__ unsigned short s_list[TP][4][32];
    __shared__ unsigned short s_A[TP * Cq];        // packed A frags [mt][kt][lane][j]
    __shared__ float s_sum[TP][4], s_sq[TP][4];

    if (t < Nq) { s_ge[t] = ge[b * Nq + t]; s_gp[t] = gp[b * Nq + t]; }
#pragma unroll
    for (int i = t; i < 9 * Cq; i += 256) s_ck[i] = ck[i];
    __syncthreads();

    // ---- match lists: thread owns (p = t>>2, sub = t&3), scans 32 candidates
    {
        int p = t >> 2, sub = t & 3;
        int th = s_ge[p0 + p], tw = s_gp[p0 + p];
        int cnt = 0;
        int mbase = sub * 32;
        unsigned short* lst = s_list[p][sub];
        for (int i = 0; i < 32; ++i) {
            int m = mbase + i;
            int dh = s_ge[m] - th, dv = s_gp[m] - tw;
            if (dh >= -1 && dh <= 1 && dv >= -1 && dv <= 1)
                lst[cnt++] = (unsigned short)(m | (((dh + 1) * 3 + dv + 1) << 8));
        }
        s_cnt[p][sub] = cnt;
    }
    __syncthreads();

    // ---- conv at the 64 gathered positions; write bf16 packed A frags ----
    {
        const int c = t;
        const float bias_c = cb[c];
        const int kt_ = c >> 5, jj = c & 7, lanehi = ((c >> 3) & 3) << 4;
        for (int p = 0; p < TP; ++p) {
            float acc = bias_c;
#pragma unroll
            for (int sub = 0; sub < 4; ++sub) {
                int cnt = s_cnt[p][sub];
                for (int i = 0; i < cnt; ++i) {
                    int e = s_list[p][sub][i];
                    int m = e & 255, kk = e >> 8;
                    acc += s_ck[kk * Cq + c] * x[(b * Nq + m) * Cq + c];
                }
            }
            int mt = p >> 4;
            int lidx = (p & 15) | lanehi;
            s_A[((mt * 8 + kt_) * 64 + lidx) * 8 + jj] = f2bf(acc);
        }
    }
    __syncthreads();

    // ---- GEMM: wave handles ntiles 4w..4w+3, all 4 mtiles, K = 8 steps ----
    f32x4 acc[4][4];   // [mt][ntl]
#pragma unroll
    for (int mt = 0; mt < 4; ++mt)
#pragma unroll
        for (int ntl = 0; ntl < 4; ++ntl) acc[mt][ntl] = (f32x4){0.f, 0.f, 0.f, 0.f};

#pragma unroll
    for (int kt2 = 0; kt2 < 8; ++kt2) {
        bf16x8 afrag[4];
#pragma unroll
        for (int mt = 0; mt < 4; ++mt)
            afrag[mt] = *reinterpret_cast<const bf16x8*>(&s_A[((mt * 8 + kt2) * 64 + lane) * 8]);
#pragma unroll
        for (int ntl = 0; ntl < 4; ++ntl) {
            int nt = wave * 4 + ntl;
            bf16x8 bfrag = *reinterpret_cast<const bf16x8*>(&wp[((kt2 * 16 + nt) * 64 + lane) * 8]);
#pragma unroll
            for (int mt = 0; mt < 4; ++mt)
                acc[mt][ntl] = __builtin_amdgcn_mfma_f32_16x16x32_bf16(afrag[mt], bfrag,
                                                                       acc[mt][ntl], 0, 0, 0);
        }
    }

    // ---- epilogue: +db, per-row LN stats (row = mt*16 + (lane>>4)*4 + r) ----
    float dbv[4], gv[4], bv[4];
#pragma unroll
    for (int ntl = 0; ntl < 4; ++ntl) {
        int col = (wave * 4 + ntl) * 16 + (lane & 15);
        dbv[ntl] = db[col]; gv[ntl] = gamma[col]; bv[ntl] = beta[col];
    }
#pragma unroll
    for (int mt = 0; mt < 4; ++mt) {
#pragma unroll
        for (int r = 0; r < 4; ++r) {
            float a = 0.f, q = 0.f;
#pragma unroll
            for (int ntl = 0; ntl < 4; ++ntl) {
                float y = acc[mt][ntl][r] + dbv[ntl];
                a += y; q += y * y;
            }
#pragma unroll
            for (int off = 8; off >= 1; off >>= 1) {
                a += __shfl_xor(a, off);
                q += __shfl_xor(q, off);
            }
            if ((lane & 15) == 0) {
                int row = mt * 16 + (lane >> 4) * 4 + r;
                s_sum[row][wave] = a;
                s_sq[row][wave]  = q;
            }
        }
    }
    __syncthreads();

#pragma unroll
    for (int mt = 0; mt < 4; ++mt) {
        int rowbase = mt * 16 + (lane >> 4) * 4;
#pragma unroll
        for (int r = 0; r < 4; ++r) {
            int row = rowbase + r;
            float s = s_sum[row][0] + s_sum[row][1] + s_sum[row][2] + s_sum[row][3];
            float q = s_sq[row][0] + s_sq[row][1] + s_sq[row][2] + s_sq[row][3];
            float mean = s * (1.0f / Cq);
            float var  = q * (1.0f / Cq) - mean * mean;
            float inv  = rsqrtf(var + 1e-6f);
            int gbase = (b * Nq + p0 + row) * Cq + wave * 64 + (lane & 15);
#pragma unroll
            for (int ntl = 0; ntl < 4; ++ntl) {
                float y = acc[mt][ntl][r] + dbv[ntl];
                int idx = gbase + ntl * 16;
                out[idx] = x[idx] + (y - mean) * inv * gv[ntl] + bv[ntl];
            }
        }
    }
}

extern "C" void kernel_launch(void* const* d_in, const int* in_sizes, int n_in,
                              void* d_out, int out_size, void* d_ws, size_t ws_size,
                              hipStream_t stream) {
    const float* x     = (const float*)d_in[0];
    const float* eta   = (const float*)d_in[1];
    const float* phi   = (const float*)d_in[2];
    const float* ck    = (const float*)d_in[3];
    const float* cb    = (const float*)d_in[4];
    const float* dw    = (const float*)d_in[5];
    const float* db    = (const float*)d_in[6];
    const float* gamma = (const float*)d_in[7];
    const float* beta  = (const float*)d_in[8];
    float* out = (float*)d_out;

    int* ge = (int*)d_ws;                       // 32768 ints
    int* gp = ge + Bq * Nq;                     // 32768 ints
    unsigned short* wpk = (unsigned short*)(gp + Bq * Nq);  // 65536 bf16

    wpack_kernel<<<Cq, 256, 0, stream>>>(dw, wpk);
    idx_kernel<<<Bq, Nq, 0, stream>>>(eta, phi, ge, gp);
    fused_kernel<<<Bq * (Nq / TP), 256, 0, stream>>>(x, ge, gp, ck, cb, wpk, db,
                                                     gamma, beta, out);
}

// Round 3
// 130.387 us; speedup vs baseline: 1.5488x; 1.2675x over previous
//
#include <hip/hip_runtime.h>

typedef __attribute__((ext_vector_type(8))) short bf16x8;
typedef __attribute__((ext_vector_type(4))) float f32x4;

#define Bq 256
#define Nq 128
#define Cq 256
#define TP 16            // particles per fused block
#define NBLK (Nq / TP)   // 8 blocks per batch

__device__ __forceinline__ unsigned short f2bf(float f) {
    unsigned int u = __float_as_uint(f);
    u += 0x7fffu + ((u >> 16) & 1u);   // RNE
    return (unsigned short)(u >> 16);
}

// -------- kernel 0: pack dense_w fp32 -> bf16 in MFMA B-fragment order ------
// wp[((kt*16 + nt)*64 + lane)*8 + j] = W[k = kt*32 + (lane>>4)*8 + j][n = nt*16 + (lane&15)]
__global__ __launch_bounds__(256) void wpack_kernel(const float* __restrict__ dw,
                                                    unsigned short* __restrict__ wp) {
    int tid = blockIdx.x * 256 + threadIdx.x;
    int j    = tid & 7;
    int lane = (tid >> 3) & 63;
    int nt   = (tid >> 9) & 15;
    int kt   = tid >> 13;
    int k = kt * 32 + (lane >> 4) * 8 + j;
    int n = nt * 16 + (lane & 15);
    wp[tid] = f2bf(dw[k * Cq + n]);
}

// -------- fused: idx + conv-at-particles + MFMA dense + LN + residual ----
__global__ __launch_bounds__(256, 5) void fused_kernel(
    const float* __restrict__ x, const float* __restrict__ eta, const float* __restrict__ phi,
    const float* __restrict__ ck, const float* __restrict__ cb,
    const unsigned short* __restrict__ wp, const float* __restrict__ db,
    const float* __restrict__ gamma, const float* __restrict__ beta,
    float* __restrict__ out) {
    const int b  = blockIdx.x >> 3;
    const int p0 = (blockIdx.x & (NBLK - 1)) * TP;
    const int t  = threadIdx.x;
    const int lane = t & 63, wave = t >> 6;

    __shared__ int   s_ge[Nq], s_gp[Nq];
    __shared__ float s_ck[9 * Cq];        // 9 KB
    __shared__ float s_min[4];            // emin{w0,w1}, pmin{w0,w1}
    __shared__ int   s_cnt[TP];
    __shared__ int   s_list[TP][Nq];      // 8 KB: (k*256)<<16 | m*256
    __shared__ unsigned short s_A[8 * 64 * 8];  // 8 KB packed bf16 A frags
    __shared__ float s_sum[TP][4], s_sq[TP][4];

    // ---- per-batch minima (waves 0-1), overlap with conv-kernel staging ----
    float ev = 0.f, pv = 0.f;
    if (t < Nq) {
        ev = eta[b * Nq + t];
        pv = phi[b * Nq + t];
        float emin = ev, pmin = pv;
#pragma unroll
        for (int off = 32; off > 0; off >>= 1) {
            emin = fminf(emin, __shfl_down(emin, off));
            pmin = fminf(pmin, __shfl_down(pmin, off));
        }
        if ((t & 63) == 0) { s_min[wave] = emin; s_min[2 + wave] = pmin; }
    }
#pragma unroll
    for (int i = t; i < 9 * Cq; i += 256) s_ck[i] = ck[i];
    if (t < TP) s_cnt[t] = 0;
    __syncthreads();

    if (t < Nq) {
        float Emin = fminf(s_min[0], s_min[1]);
        float Pmin = fminf(s_min[2], s_min[3]);
        s_ge[t] = (int)((ev - Emin) / 0.05f);   // bit-match numpy fp32 path
        s_gp[t] = (int)((pv - Pmin) / 0.05f);
    }
    __syncthreads();

    // ---- match scan: thread owns (pp = t>>4, sub = t&15), 8 candidates ----
    {
        int pp = t >> 4, sub = t & 15;
        int th = s_ge[p0 + pp], tw = s_gp[p0 + pp];
#pragma unroll
        for (int i = 0; i < 8; ++i) {
            int m = sub * 8 + i;
            int dh = s_ge[m] - th, dv = s_gp[m] - tw;
            if (dh >= -1 && dh <= 1 && dv >= -1 && dv <= 1) {
                int k = (dh + 1) * 3 + (dv + 1);   // cross-correlation tap
                int pos = atomicAdd(&s_cnt[pp], 1);
                s_list[pp][pos] = ((k * Cq) << 16) | (m * Cq);
            }
        }
    }
    __syncthreads();

    // ---- conv at the TP gathered positions; write swizzled bf16 A frags ----
    {
        const int c = t;
        const float bias_c = cb[c];
        const int kt = c >> 5, g = (c >> 3) & 3, jj = c & 7;
        const float* xb = x + (size_t)b * Nq * Cq + c;
        for (int pp = 0; pp < TP; ++pp) {
            float acc = bias_c;
            int cnt = s_cnt[pp];
            const int* lst = s_list[pp];
            for (int i = 0; i < cnt; ++i) {
                int e = lst[i];
                acc += s_ck[(e >> 16) + c] * xb[e & 0xffff];
            }
            // swizzle: chunk lane-index XORed by 2*lane-group to spread banks
            int lidx = ((pp + 2 * g) & 15) | (g << 4);
            s_A[(kt * 64 + lidx) * 8 + jj] = f2bf(acc);
        }
    }
    __syncthreads();

    // ---- GEMM: 1 mtile x 4 ntl per wave, K = 8 steps of 32 ----
    f32x4 acc[4];
#pragma unroll
    for (int ntl = 0; ntl < 4; ++ntl) acc[ntl] = (f32x4){0.f, 0.f, 0.f, 0.f};

    const int g2 = lane >> 4, m2 = lane & 15;
    const int alidx = ((m2 + 2 * g2) & 15) | (g2 << 4);
#pragma unroll
    for (int kt2 = 0; kt2 < 8; ++kt2) {
        bf16x8 af = *reinterpret_cast<const bf16x8*>(&s_A[(kt2 * 64 + alidx) * 8]);
#pragma unroll
        for (int ntl = 0; ntl < 4; ++ntl) {
            int nt = wave * 4 + ntl;
            bf16x8 bfr = *reinterpret_cast<const bf16x8*>(&wp[((kt2 * 16 + nt) * 64 + lane) * 8]);
            acc[ntl] = __builtin_amdgcn_mfma_f32_16x16x32_bf16(af, bfr, acc[ntl], 0, 0, 0);
        }
    }

    // ---- epilogue: +db, LN stats per row (row = g2*4 + r), residual ----
    float dbv[4], gv[4], bv[4];
#pragma unroll
    for (int ntl = 0; ntl < 4; ++ntl) {
        int col = (wave * 4 + ntl) * 16 + m2;
        dbv[ntl] = db[col]; gv[ntl] = gamma[col]; bv[ntl] = beta[col];
    }
#pragma unroll
    for (int r = 0; r < 4; ++r) {
        float a = 0.f, q = 0.f;
#pragma unroll
        for (int ntl = 0; ntl < 4; ++ntl) {
            float y = acc[ntl][r] + dbv[ntl];
            a += y; q += y * y;
        }
#pragma unroll
        for (int off = 8; off >= 1; off >>= 1) {
            a += __shfl_xor(a, off);
            q += __shfl_xor(q, off);
        }
        if (m2 == 0) {
            int row = g2 * 4 + r;
            s_sum[row][wave] = a;
            s_sq[row][wave]  = q;
        }
    }
    __syncthreads();

#pragma unroll
    for (int r = 0; r < 4; ++r) {
        int row = g2 * 4 + r;
        float s = s_sum[row][0] + s_sum[row][1] + s_sum[row][2] + s_sum[row][3];
        float q = s_sq[row][0] + s_sq[row][1] + s_sq[row][2] + s_sq[row][3];
        float mean = s * (1.0f / Cq);
        float var  = q * (1.0f / Cq) - mean * mean;
        float inv  = rsqrtf(var + 1e-6f);
        int gbase = (b * Nq + p0 + row) * Cq + wave * 64 + m2;
#pragma unroll
        for (int ntl = 0; ntl < 4; ++ntl) {
            float y = acc[ntl][r] + dbv[ntl];
            int idx = gbase + ntl * 16;
            out[idx] = x[idx] + (y - mean) * inv * gv[ntl] + bv[ntl];
        }
    }
}

extern "C" void kernel_launch(void* const* d_in, const int* in_sizes, int n_in,
                              void* d_out, int out_size, void* d_ws, size_t ws_size,
                              hipStream_t stream) {
    const float* x     = (const float*)d_in[0];
    const float* eta   = (const float*)d_in[1];
    const float* phi   = (const float*)d_in[2];
    const float* ck    = (const float*)d_in[3];
    const float* cb    = (const float*)d_in[4];
    const float* dw    = (const float*)d_in[5];
    const float* db    = (const float*)d_in[6];
    const float* gamma = (const float*)d_in[7];
    const float* beta  = (const float*)d_in[8];
    float* out = (float*)d_out;

    unsigned short* wpk = (unsigned short*)d_ws;   // 65536 bf16

    wpack_kernel<<<Cq, 256, 0, stream>>>(dw, wpk);
    fused_kernel<<<Bq * NBLK, 256, 0, stream>>>(x, eta, phi, ck, cb, wpk, db,
                                                gamma, beta, out);
}

// Round 4
// 119.536 us; speedup vs baseline: 1.6894x; 1.0908x over previous
//
#include <hip/hip_runtime.h>

typedef __attribute__((ext_vector_type(8))) short bf16x8;
typedef __attribute__((ext_vector_type(4))) float f32x4;

#define Bq 256
#define Nq 128
#define Cq 256
#define TP 16            // particles per fused block
#define NBLK (Nq / TP)   // 8 blocks per batch

__device__ __forceinline__ unsigned short f2bf(float f) {
    unsigned int u = __float_as_uint(f);
    u += 0x7fffu + ((u >> 16) & 1u);   // RNE
    return (unsigned short)(u >> 16);
}

struct ushort4_t { unsigned short x, y, z, w; };

__device__ __forceinline__ void fma4(float4& a, const float4& k, const float4& x) {
    a.x = fmaf(k.x, x.x, a.x);
    a.y = fmaf(k.y, x.y, a.y);
    a.z = fmaf(k.z, x.z, a.z);
    a.w = fmaf(k.w, x.w, a.w);
}

// -------- kernel 0: pack dense_w fp32 -> bf16 in MFMA B-fragment order ------
// wp[((kt*16 + nt)*64 + lane)*8 + j] = W[k = kt*32 + (lane>>4)*8 + j][n = nt*16 + (lane&15)]
__global__ __launch_bounds__(256) void wpack_kernel(const float* __restrict__ dw,
                                                    unsigned short* __restrict__ wp) {
    int tid = blockIdx.x * 256 + threadIdx.x;
    int j    = tid & 7;
    int lane = (tid >> 3) & 63;
    int nt   = (tid >> 9) & 15;
    int kt   = tid >> 13;
    int k = kt * 32 + (lane >> 4) * 8 + j;
    int n = nt * 16 + (lane & 15);
    wp[tid] = f2bf(dw[k * Cq + n]);
}

// -------- fused: idx + conv-at-particles + MFMA dense + LN + residual ----
__global__ __launch_bounds__(256, 4) void fused_kernel(
    const float* __restrict__ x, const float* __restrict__ eta, const float* __restrict__ phi,
    const float* __restrict__ ck, const float* __restrict__ cb,
    const unsigned short* __restrict__ wp, const float* __restrict__ db,
    const float* __restrict__ gamma, const float* __restrict__ beta,
    float* __restrict__ out) {
    const int b  = blockIdx.x >> 3;
    const int p0 = (blockIdx.x & (NBLK - 1)) * TP;
    const int t  = threadIdx.x;
    const int lane = t & 63, wave = t >> 6;

    __shared__ int   s_ge[Nq], s_gp[Nq];
    __shared__ float s_ck[10 * Cq];                 // 10 KB, row 9 = zeros (pad tap)
    __shared__ float s_min[4];
    __shared__ int   s_cnt[TP];
    __shared__ unsigned short s_list[TP][132];      // m | (k<<7)
    __shared__ unsigned short s_A[8 * 64 * 8] __attribute__((aligned(16)));  // 8 KB
    __shared__ float s_sum[TP][4], s_sq[TP][4];

    // ---- per-batch minima (threads 0..127) + ck staging + zero pad row ----
    float ev = 0.f, pv = 0.f;
    if (t < Nq) {
        ev = eta[b * Nq + t];
        pv = phi[b * Nq + t];
        float emin = ev, pmin = pv;
#pragma unroll
        for (int off = 32; off > 0; off >>= 1) {
            emin = fminf(emin, __shfl_down(emin, off));
            pmin = fminf(pmin, __shfl_down(pmin, off));
        }
        if ((t & 63) == 0) { s_min[wave] = emin; s_min[2 + wave] = pmin; }
    }
#pragma unroll
    for (int i = t; i < 9 * Cq; i += 256) s_ck[i] = ck[i];
    s_ck[9 * Cq + t] = 0.0f;
    if (t < TP) s_cnt[t] = 0;
    __syncthreads();

    if (t < Nq) {
        float Emin = fminf(s_min[0], s_min[1]);
        float Pmin = fminf(s_min[2], s_min[3]);
        s_ge[t] = (int)((ev - Emin) / 0.05f);   // bit-match numpy fp32 path
        s_gp[t] = (int)((pv - Pmin) / 0.05f);
    }
    __syncthreads();

    const int pp = t >> 4, cg = t & 15;

    // ---- match scan: thread (pp, sub=cg) scans 8 candidates ----
    {
        int th = s_ge[p0 + pp], tw = s_gp[p0 + pp];
#pragma unroll
        for (int i = 0; i < 8; ++i) {
            int m = cg * 8 + i;
            int dh = s_ge[m] - th, dv = s_gp[m] - tw;
            if (dh >= -1 && dh <= 1 && dv >= -1 && dv <= 1) {
                int k = (dh + 1) * 3 + (dv + 1);   // cross-correlation tap
                int pos = atomicAdd(&s_cnt[pp], 1);
                s_list[pp][pos] = (unsigned short)(m | (k << 7));
            }
        }
    }
    __syncthreads();
    if (t < TP) {                       // pad each list to even count (zero tap 9)
        int c = s_cnt[t];
        if (c & 1) { s_list[t][c] = (unsigned short)(9 << 7); s_cnt[t] = c + 1; }
    }
    __syncthreads();

    // ---- conv: thread = (pp, cg); channels c = j*64 + cg*4 + i ----
    {
        const float4* x4  = (const float4*)x + (size_t)b * (Nq * Cq / 4) + cg;
        const float4* ck4 = (const float4*)s_ck + cg;
        const float4* cb4 = (const float4*)cb + cg;
        float4 a0 = cb4[0], a1 = cb4[16], a2 = cb4[32], a3 = cb4[48];

        const int cnt = s_cnt[pp];
        const unsigned short* lst = s_list[pp];
        for (int i = 0; i < cnt; i += 2) {
            int e0 = lst[i], e1 = lst[i + 1];
            const float4* xp0 = x4  + ((e0 & 127) << 6);
            const float4* kp0 = ck4 + ((e0 >> 7)  << 6);
            const float4* xp1 = x4  + ((e1 & 127) << 6);
            const float4* kp1 = ck4 + ((e1 >> 7)  << 6);
            float4 X00 = xp0[0], X01 = xp0[16], X02 = xp0[32], X03 = xp0[48];
            float4 X10 = xp1[0], X11 = xp1[16], X12 = xp1[32], X13 = xp1[48];
            float4 K00 = kp0[0], K01 = kp0[16], K02 = kp0[32], K03 = kp0[48];
            float4 K10 = kp1[0], K11 = kp1[16], K12 = kp1[32], K13 = kp1[48];
            fma4(a0, K00, X00); fma4(a1, K01, X01);
            fma4(a2, K02, X02); fma4(a3, K03, X03);
            fma4(a0, K10, X10); fma4(a1, K11, X11);
            fma4(a2, K12, X12); fma4(a3, K13, X13);
        }

        // write swizzled bf16 A-fragments: per j one 8-byte store
        const int g = (cg >> 1) & 3;
        const int lidx = ((pp + 2 * g) & 15) | (g << 4);
        const int off = (cg & 1) * 4;
        float4 aj[4] = {a0, a1, a2, a3};
#pragma unroll
        for (int j = 0; j < 4; ++j) {
            int kt = j * 2 + (cg >> 3);
            ushort4_t v;
            v.x = f2bf(aj[j].x); v.y = f2bf(aj[j].y);
            v.z = f2bf(aj[j].z); v.w = f2bf(aj[j].w);
            *(ushort4_t*)&s_A[(kt * 64 + lidx) * 8 + off] = v;
        }
    }
    __syncthreads();

    // ---- GEMM: 1 mtile x 4 ntl per wave, K = 8 steps of 32 ----
    f32x4 acc[4];
#pragma unroll
    for (int ntl = 0; ntl < 4; ++ntl) acc[ntl] = (f32x4){0.f, 0.f, 0.f, 0.f};

    const int g2 = lane >> 4, m2 = lane & 15;
    const int alidx = ((m2 + 2 * g2) & 15) | (g2 << 4);
#pragma unroll
    for (int kt2 = 0; kt2 < 8; ++kt2) {
        bf16x8 af = *reinterpret_cast<const bf16x8*>(&s_A[(kt2 * 64 + alidx) * 8]);
#pragma unroll
        for (int ntl = 0; ntl < 4; ++ntl) {
            int nt = wave * 4 + ntl;
            bf16x8 bfr = *reinterpret_cast<const bf16x8*>(&wp[((kt2 * 16 + nt) * 64 + lane) * 8]);
            acc[ntl] = __builtin_amdgcn_mfma_f32_16x16x32_bf16(af, bfr, acc[ntl], 0, 0, 0);
        }
    }

    // ---- epilogue: +db, LN stats per row (row = g2*4 + r), residual ----
    float dbv[4], gv[4], bv[4];
#pragma unroll
    for (int ntl = 0; ntl < 4; ++ntl) {
        int col = (wave * 4 + ntl) * 16 + m2;
        dbv[ntl] = db[col]; gv[ntl] = gamma[col]; bv[ntl] = beta[col];
    }
#pragma unroll
    for (int r = 0; r < 4; ++r) {
        float a = 0.f, q = 0.f;
#pragma unroll
        for (int ntl = 0; ntl < 4; ++ntl) {
            float y = acc[ntl][r] + dbv[ntl];
            a += y; q += y * y;
        }
#pragma unroll
        for (int off = 8; off >= 1; off >>= 1) {
            a += __shfl_xor(a, off);
            q += __shfl_xor(q, off);
        }
        if (m2 == 0) {
            int row = g2 * 4 + r;
            s_sum[row][wave] = a;
            s_sq[row][wave]  = q;
        }
    }
    __syncthreads();

#pragma unroll
    for (int r = 0; r < 4; ++r) {
        int row = g2 * 4 + r;
        float s = s_sum[row][0] + s_sum[row][1] + s_sum[row][2] + s_sum[row][3];
        float q = s_sq[row][0] + s_sq[row][1] + s_sq[row][2] + s_sq[row][3];
        float mean = s * (1.0f / Cq);
        float var  = q * (1.0f / Cq) - mean * mean;
        float inv  = rsqrtf(var + 1e-6f);
        int gbase = (b * Nq + p0 + row) * Cq + wave * 64 + m2;
#pragma unroll
        for (int ntl = 0; ntl < 4; ++ntl) {
            float y = acc[ntl][r] + dbv[ntl];
            int idx = gbase + ntl * 16;
            out[idx] = x[idx] + (y - mean) * inv * gv[ntl] + bv[ntl];
        }
    }
}

extern "C" void kernel_launch(void* const* d_in, const int* in_sizes, int n_in,
                              void* d_out, int out_size, void* d_ws, size_t ws_size,
                              hipStream_t stream) {
    const float* x     = (const float*)d_in[0];
    const float* eta   = (const float*)d_in[1];
    const float* phi   = (const float*)d_in[2];
    const float* ck    = (const float*)d_in[3];
    const float* cb    = (const float*)d_in[4];
    const float* dw    = (const float*)d_in[5];
    const float* db    = (const float*)d_in[6];
    const float* gamma = (const float*)d_in[7];
    const float* beta  = (const float*)d_in[8];
    float* out = (float*)d_out;

    unsigned short* wpk = (unsigned short*)d_ws;   // 65536 bf16

    wpack_kernel<<<Cq, 256, 0, stream>>>(dw, wpk);
    fused_kernel<<<Bq * NBLK, 256, 0, stream>>>(x, eta, phi, ck, cb, wpk, db,
                                                gamma, beta, out);
}